// Round 1
// baseline (977.217 us; speedup 1.0000x reference)
//
#include <hip/hip_runtime.h>
#include <hip/hip_bf16.h>

#define H 10
#define T_LEN 2048
#define BATCH 8192

// ---------------------------------------------------------------------------
// Kernel 1: Bmat = expm(triu(A,1) - triu(A,1)^T) in fp64, write fp32 to ws.
// Single block, 128 threads (threads 0..99 own element (i,j)).
// Fixed scaling s=8 (||S||_1 ~ 1 << 256), 16 Taylor terms, 8 squarings.
// ---------------------------------------------------------------------------
__global__ void expm_kernel(const float* __restrict__ A, float* __restrict__ Bout) {
    __shared__ double S[H][H];
    __shared__ double P[H][H];
    __shared__ double E[H][H];
    const int tid = threadIdx.x;
    const int i = tid / H, j = tid % H;
    if (tid < H * H) {
        double a = 0.0;
        if (i < j) a = (double)A[i * H + j];
        else if (i > j) a = -(double)A[j * H + i];
        a *= (1.0 / 256.0);          // scale by 2^-8
        S[i][j] = a;
        P[i][j] = a;                 // S^1 / 1!
        E[i][j] = (i == j ? 1.0 : 0.0) + a;
    }
    __syncthreads();
    // Taylor terms k = 2..16: P = P*S/k ; E += P
    for (int k = 2; k <= 16; ++k) {
        double acc = 0.0;
        if (tid < H * H) {
            for (int m = 0; m < H; ++m) acc += P[i][m] * S[m][j];
            acc *= (1.0 / (double)k);
        }
        __syncthreads();
        if (tid < H * H) { P[i][j] = acc; E[i][j] += acc; }
        __syncthreads();
    }
    // square 8 times: E = E*E
    for (int r = 0; r < 8; ++r) {
        double acc = 0.0;
        if (tid < H * H) {
            for (int m = 0; m < H; ++m) acc += E[i][m] * E[m][j];
        }
        __syncthreads();
        if (tid < H * H) E[i][j] = acc;
        __syncthreads();
    }
    if (tid < H * H) Bout[i * H + j] = (float)E[i][j];
}

// ---------------------------------------------------------------------------
// Kernel 2: the recurrence. One thread per batch element. h[10], Bmat, W_in,
// b_mod, lin_W all live in registers. Inputs are streamed 64B/lane per 8
// steps (per-thread-contiguous layout [b][t][2]), software-pipelined one
// chunk ahead.
// ---------------------------------------------------------------------------
__global__ __launch_bounds__(64, 1)
void rnn_kernel(const float* __restrict__ x,
                const float* __restrict__ Bm_g,
                const float* __restrict__ Win,
                const float* __restrict__ bmod,
                const float* __restrict__ lW,
                const float* __restrict__ lb,
                float* __restrict__ out) {
    const int b = blockIdx.x * 64 + threadIdx.x;

    // uniform parameters -> registers
    float Bm[H][H];
#pragma unroll
    for (int i = 0; i < H; ++i)
#pragma unroll
        for (int j = 0; j < H; ++j) Bm[i][j] = Bm_g[i * H + j];

    float w0[H], w1[H], bm[H], h[H];
#pragma unroll
    for (int j = 0; j < H; ++j) {
        w0[j] = Win[j * 2 + 0];
        w1[j] = Win[j * 2 + 1];
        bm[j] = bmod[j];
        h[j] = 0.0f;
    }

    const float4* __restrict__ xp4 =
        (const float4*)(x + (size_t)b * (T_LEN * 2));  // 1024 float4 per row

    // prologue: load chunk 0 (8 steps = 4 float4)
    float4 buf0 = xp4[0], buf1 = xp4[1], buf2 = xp4[2], buf3 = xp4[3];

    for (int t0 = 0; t0 < T_LEN; t0 += 8) {
        const float4 c0 = buf0, c1 = buf1, c2 = buf2, c3 = buf3;
        // prefetch next chunk
        if (t0 + 8 < T_LEN) {
            const int base = (t0 + 8) >> 1;  // float4 index
            buf0 = xp4[base + 0];
            buf1 = xp4[base + 1];
            buf2 = xp4[base + 2];
            buf3 = xp4[base + 3];
        }
        float xs[16];
        xs[0] = c0.x; xs[1] = c0.y; xs[2] = c0.z; xs[3] = c0.w;
        xs[4] = c1.x; xs[5] = c1.y; xs[6] = c1.z; xs[7] = c1.w;
        xs[8] = c2.x; xs[9] = c2.y; xs[10] = c2.z; xs[11] = c2.w;
        xs[12] = c3.x; xs[13] = c3.y; xs[14] = c3.z; xs[15] = c3.w;

#pragma unroll
        for (int u = 0; u < 8; ++u) {
            const float x0 = xs[2 * u], x1 = xs[2 * u + 1];
            float acc[H];
#pragma unroll
            for (int j = 0; j < H; ++j)
                acc[j] = fmaf(x1, w1[j], x0 * w0[j]);
#pragma unroll
            for (int i = 0; i < H; ++i) {
                const float hi = h[i];
#pragma unroll
                for (int j = 0; j < H; ++j)
                    acc[j] = fmaf(hi, Bm[i][j], acc[j]);
            }
#pragma unroll
            for (int j = 0; j < H; ++j) {
                const float z = acc[j];
                const float r = fmaxf(fabsf(z) + bm[j], 0.0f);
                h[j] = __builtin_copysignf(r, z);
            }
        }
    }

    // epilogue: out[b][o] = sum_j h[j] * lin_W[o][j] + lin_b[o]
#pragma unroll
    for (int o = 0; o < H; ++o) {
        float acc = lb[o];
#pragma unroll
        for (int j = 0; j < H; ++j) acc = fmaf(h[j], lW[o * H + j], acc);
        out[(size_t)b * H + o] = acc;
    }
}

extern "C" void kernel_launch(void* const* d_in, const int* in_sizes, int n_in,
                              void* d_out, int out_size, void* d_ws, size_t ws_size,
                              hipStream_t stream) {
    const float* inputs = (const float*)d_in[0];  // [8192, 2048, 2]
    const float* A      = (const float*)d_in[1];  // [10, 10]
    const float* W_in   = (const float*)d_in[2];  // [10, 2]
    const float* b_mod  = (const float*)d_in[3];  // [10]
    const float* lin_W  = (const float*)d_in[4];  // [10, 10]
    const float* lin_b  = (const float*)d_in[5];  // [10]
    float* out = (float*)d_out;                   // [8192, 10]
    float* Bmat = (float*)d_ws;                   // 100 floats scratch

    expm_kernel<<<1, 128, 0, stream>>>(A, Bmat);
    rnn_kernel<<<BATCH / 64, 64, 0, stream>>>(inputs, Bmat, W_in, b_mod,
                                              lin_W, lin_b, out);
}

// Round 2
// 392.667 us; speedup vs baseline: 2.4887x; 2.4887x over previous
//
#include <hip/hip_runtime.h>
#include <hip/hip_bf16.h>

#define H 10
#define T_LEN 2048
#define BATCH 8192

// ---------------------------------------------------------------------------
// Kernel 1: Bmat = expm(triu(A,1) - triu(A,1)^T) in fp64, write fp32 to ws.
// Single block, 128 threads (threads 0..99 own element (i,j)).
// Fixed scaling s=8 (||S||_1 ~ 1 << 256), 16 Taylor terms, 8 squarings.
// ---------------------------------------------------------------------------
__global__ void expm_kernel(const float* __restrict__ A, float* __restrict__ Bout) {
    __shared__ double S[H][H];
    __shared__ double P[H][H];
    __shared__ double E[H][H];
    const int tid = threadIdx.x;
    const int i = tid / H, j = tid % H;
    if (tid < H * H) {
        double a = 0.0;
        if (i < j) a = (double)A[i * H + j];
        else if (i > j) a = -(double)A[j * H + i];
        a *= (1.0 / 256.0);          // scale by 2^-8
        S[i][j] = a;
        P[i][j] = a;                 // S^1 / 1!
        E[i][j] = (i == j ? 1.0 : 0.0) + a;
    }
    __syncthreads();
    // Taylor terms k = 2..16: P = P*S/k ; E += P
    for (int k = 2; k <= 16; ++k) {
        double acc = 0.0;
        if (tid < H * H) {
            for (int m = 0; m < H; ++m) acc += P[i][m] * S[m][j];
            acc *= (1.0 / (double)k);
        }
        __syncthreads();
        if (tid < H * H) { P[i][j] = acc; E[i][j] += acc; }
        __syncthreads();
    }
    // square 8 times: E = E*E
    for (int r = 0; r < 8; ++r) {
        double acc = 0.0;
        if (tid < H * H) {
            for (int m = 0; m < H; ++m) acc += E[i][m] * E[m][j];
        }
        __syncthreads();
        if (tid < H * H) E[i][j] = acc;
        __syncthreads();
    }
    if (tid < H * H) Bout[i * H + j] = (float)E[i][j];
}

// ---------------------------------------------------------------------------
// Kernel 2: lane-parallel recurrence. Each 16-lane group owns one batch
// element; lane r (r<10) owns h[r]. The matvec h@B is 10 broadcasts
// (ds_swizzle, src lane = (lane&0x10)|i within each 32-half) + 10 FMAs.
// 8192 batches / 4 groups per wave = 2048 waves -> 2 waves/SIMD device-wide.
// ---------------------------------------------------------------------------

// broadcast lane i (within 16-group) of h to all lanes of the group
#define GBCAST(hbits, i) \
    __int_as_float(__builtin_amdgcn_ds_swizzle((hbits), ((i) << 5) | 0x10))

__global__ __launch_bounds__(256, 2)
void rnn_kernel(const float* __restrict__ x,
                const float* __restrict__ Bm_g,
                const float* __restrict__ Win,
                const float* __restrict__ bmod,
                const float* __restrict__ lW,
                const float* __restrict__ lb,
                float* __restrict__ out) {
    const int r  = threadIdx.x & 15;              // lane within group
    const int bb = blockIdx.x * 16 + (threadIdx.x >> 4);  // batch element
    const int j  = (r < H) ? r : (H - 1);         // owned hidden index (clamped)

    // per-lane column of B: Bcol[i] = Bm[i][j]
    float Bcol[H];
#pragma unroll
    for (int i = 0; i < H; ++i) Bcol[i] = Bm_g[i * H + j];

    const float w0 = Win[j * 2 + 0];
    const float w1 = Win[j * 2 + 1];
    const float bm = bmod[j];
    float h = 0.0f;

    const float4* __restrict__ xp4 =
        (const float4*)(x + (size_t)bb * (T_LEN * 2));  // shared across group

    // prologue: chunk 0 (8 steps = 4 float4, same address for all 16 lanes)
    float4 buf0 = xp4[0], buf1 = xp4[1], buf2 = xp4[2], buf3 = xp4[3];

    for (int t0 = 0; t0 < T_LEN; t0 += 8) {
        const float4 c0 = buf0, c1 = buf1, c2 = buf2, c3 = buf3;
        if (t0 + 8 < T_LEN) {
            const int base = (t0 + 8) >> 1;
            buf0 = xp4[base + 0];
            buf1 = xp4[base + 1];
            buf2 = xp4[base + 2];
            buf3 = xp4[base + 3];
        }
        float xs[16];
        xs[0] = c0.x; xs[1] = c0.y; xs[2]  = c0.z; xs[3]  = c0.w;
        xs[4] = c1.x; xs[5] = c1.y; xs[6]  = c1.z; xs[7]  = c1.w;
        xs[8] = c2.x; xs[9] = c2.y; xs[10] = c2.z; xs[11] = c2.w;
        xs[12] = c3.x; xs[13] = c3.y; xs[14] = c3.z; xs[15] = c3.w;

#pragma unroll
        for (int u = 0; u < 8; ++u) {
            const float x0 = xs[2 * u], x1 = xs[2 * u + 1];
            float acc = fmaf(x1, w1, x0 * w0);
            const int hbits = __float_as_int(h);
            acc = fmaf(GBCAST(hbits, 0), Bcol[0], acc);
            acc = fmaf(GBCAST(hbits, 1), Bcol[1], acc);
            acc = fmaf(GBCAST(hbits, 2), Bcol[2], acc);
            acc = fmaf(GBCAST(hbits, 3), Bcol[3], acc);
            acc = fmaf(GBCAST(hbits, 4), Bcol[4], acc);
            acc = fmaf(GBCAST(hbits, 5), Bcol[5], acc);
            acc = fmaf(GBCAST(hbits, 6), Bcol[6], acc);
            acc = fmaf(GBCAST(hbits, 7), Bcol[7], acc);
            acc = fmaf(GBCAST(hbits, 8), Bcol[8], acc);
            acc = fmaf(GBCAST(hbits, 9), Bcol[9], acc);
            const float rr = fmaxf(fabsf(acc) + bm, 0.0f);
            h = __builtin_copysignf(rr, acc);
        }
    }

    // epilogue: out[bb][r] = lb[r] + sum_j h[j] * lW[r*H + j]  (lanes r<10)
    const int hbits = __float_as_int(h);
    float hb[H];
    hb[0] = GBCAST(hbits, 0); hb[1] = GBCAST(hbits, 1);
    hb[2] = GBCAST(hbits, 2); hb[3] = GBCAST(hbits, 3);
    hb[4] = GBCAST(hbits, 4); hb[5] = GBCAST(hbits, 5);
    hb[6] = GBCAST(hbits, 6); hb[7] = GBCAST(hbits, 7);
    hb[8] = GBCAST(hbits, 8); hb[9] = GBCAST(hbits, 9);
    if (r < H) {
        float acc = lb[r];
#pragma unroll
        for (int jj = 0; jj < H; ++jj) acc = fmaf(hb[jj], lW[r * H + jj], acc);
        out[(size_t)bb * H + r] = acc;
    }
}

extern "C" void kernel_launch(void* const* d_in, const int* in_sizes, int n_in,
                              void* d_out, int out_size, void* d_ws, size_t ws_size,
                              hipStream_t stream) {
    const float* inputs = (const float*)d_in[0];  // [8192, 2048, 2]
    const float* A      = (const float*)d_in[1];  // [10, 10]
    const float* W_in   = (const float*)d_in[2];  // [10, 2]
    const float* b_mod  = (const float*)d_in[3];  // [10]
    const float* lin_W  = (const float*)d_in[4];  // [10, 10]
    const float* lin_b  = (const float*)d_in[5];  // [10]
    float* out = (float*)d_out;                   // [8192, 10]
    float* Bmat = (float*)d_ws;                   // 100 floats scratch

    expm_kernel<<<1, 128, 0, stream>>>(A, Bmat);
    rnn_kernel<<<BATCH / 16, 256, 0, stream>>>(inputs, Bmat, W_in, b_mod,
                                               lin_W, lin_b, out);
}

// Round 3
// 360.829 us; speedup vs baseline: 2.7083x; 1.0882x over previous
//
#include <hip/hip_runtime.h>
#include <hip/hip_bf16.h>

#define H 10
#define T_LEN 2048
#define BATCH 8192
#define GPW 6          // batch groups per wave (10 lanes each; lanes 60-63 idle)

// ---------------------------------------------------------------------------
// Kernel 1: Bmat = expm(triu(A,1) - triu(A,1)^T) in fp64, write fp32 to ws.
// Single block, 128 threads. Fixed scaling s=8, 16 Taylor terms, 8 squarings.
// ---------------------------------------------------------------------------
__global__ void expm_kernel(const float* __restrict__ A, float* __restrict__ Bout) {
    __shared__ double S[H][H];
    __shared__ double P[H][H];
    __shared__ double E[H][H];
    const int tid = threadIdx.x;
    const int i = tid / H, j = tid % H;
    if (tid < H * H) {
        double a = 0.0;
        if (i < j) a = (double)A[i * H + j];
        else if (i > j) a = -(double)A[j * H + i];
        a *= (1.0 / 256.0);          // scale by 2^-8
        S[i][j] = a;
        P[i][j] = a;                 // S^1 / 1!
        E[i][j] = (i == j ? 1.0 : 0.0) + a;
    }
    __syncthreads();
    for (int k = 2; k <= 16; ++k) {
        double acc = 0.0;
        if (tid < H * H) {
            for (int m = 0; m < H; ++m) acc += P[i][m] * S[m][j];
            acc *= (1.0 / (double)k);
        }
        __syncthreads();
        if (tid < H * H) { P[i][j] = acc; E[i][j] += acc; }
        __syncthreads();
    }
    for (int rr = 0; rr < 8; ++rr) {
        double acc = 0.0;
        if (tid < H * H) {
            for (int m = 0; m < H; ++m) acc += E[i][m] * E[m][j];
        }
        __syncthreads();
        if (tid < H * H) E[i][j] = acc;
        __syncthreads();
    }
    if (tid < H * H) Bout[i * H + j] = (float)E[i][j];
}

// ---------------------------------------------------------------------------
// Kernel 2: 10-lane groups, LDS h-exchange.
//   lane r of group g owns h[r]; per step: 1 ds_write_b32 + (b128,b128,b64)
//   reads = 4 DS instr/wave-step (vs 10 swizzles before), 6 batches/wave.
//   Single-wave blocks -> __syncthreads() is barrier-free (lgkmcnt only).
//   Group LDS stride = 12 floats (48 B): keeps 16B alignment for b128 and
//   spreads the 6 group bases across disjoint bank quads.
// ---------------------------------------------------------------------------
__global__ __launch_bounds__(64)
void rnn_kernel(const float* __restrict__ x,
                const float* __restrict__ Bm_g,
                const float* __restrict__ Win,
                const float* __restrict__ bmod,
                const float* __restrict__ lW,
                const float* __restrict__ lb,
                float* __restrict__ out) {
    __shared__ float hsh[(GPW + 1) * 12];   // +1 scratch group for lanes 60-63

    const int lane = threadIdx.x;
    const int g = lane / 10;                // 0..6 (6 = scratch)
    const int r = lane - g * 10;            // 0..9
    const int bb_raw = blockIdx.x * GPW + g;
    const bool active = (g < GPW) && (bb_raw < BATCH);
    const int bb = active ? bb_raw : 0;     // safe address for inactive lanes
    float* const hb = &hsh[g * 12];

    // per-lane column r of B: Bcol[i] = Bm[i][r]
    float Bcol[H];
#pragma unroll
    for (int i = 0; i < H; ++i) Bcol[i] = Bm_g[i * H + r];
    const float w0 = Win[r * 2 + 0];
    const float w1 = Win[r * 2 + 1];
    const float bm = bmod[r];
    float h = 0.0f;

    const float4* __restrict__ xp4 =
        (const float4*)(x + (size_t)bb * (T_LEN * 2));  // shared across group

    float4 buf0 = xp4[0], buf1 = xp4[1], buf2 = xp4[2], buf3 = xp4[3];

    for (int t0 = 0; t0 < T_LEN; t0 += 8) {
        const float4 c0 = buf0, c1 = buf1, c2 = buf2, c3 = buf3;
        if (t0 + 8 < T_LEN) {
            const int base = (t0 + 8) >> 1;
            buf0 = xp4[base + 0];
            buf1 = xp4[base + 1];
            buf2 = xp4[base + 2];
            buf3 = xp4[base + 3];
        }
        float xs[16];
        xs[0] = c0.x; xs[1] = c0.y; xs[2]  = c0.z; xs[3]  = c0.w;
        xs[4] = c1.x; xs[5] = c1.y; xs[6]  = c1.z; xs[7]  = c1.w;
        xs[8] = c2.x; xs[9] = c2.y; xs[10] = c2.z; xs[11] = c2.w;
        xs[12] = c3.x; xs[13] = c3.y; xs[14] = c3.z; xs[15] = c3.w;

#pragma unroll
        for (int u = 0; u < 8; ++u) {
            const float x0 = xs[2 * u], x1 = xs[2 * u + 1];
            // publish h, then read the whole group vector back
            hb[r] = h;
            __syncthreads();   // single-wave block: compiles to lgkmcnt wait
            const float4 ha = *(const float4*)(hb);       // h[0..3]
            const float4 hbv = *(const float4*)(hb + 4);  // h[4..7]
            const float2 hc = *(const float2*)(hb + 8);   // h[8..9]

            float acc = fmaf(x1, w1, x0 * w0);
            // two independent 5-FMA chains to halve dependent latency
            float cA = ha.x * Bcol[0];
            float cB = ha.y * Bcol[1];
            cA = fmaf(ha.z,  Bcol[2], cA);
            cB = fmaf(ha.w,  Bcol[3], cB);
            cA = fmaf(hbv.x, Bcol[4], cA);
            cB = fmaf(hbv.y, Bcol[5], cB);
            cA = fmaf(hbv.z, Bcol[6], cA);
            cB = fmaf(hbv.w, Bcol[7], cB);
            cA = fmaf(hc.x,  Bcol[8], cA);
            cB = fmaf(hc.y,  Bcol[9], cB);
            acc = acc + cA + cB;

            const float rr = fmaxf(fabsf(acc) + bm, 0.0f);
            h = __builtin_copysignf(rr, acc);
        }
    }

    // epilogue: publish final h, each lane r computes out[bb][r]
    hb[r] = h;
    __syncthreads();
    const float4 ha = *(const float4*)(hb);
    const float4 hbv = *(const float4*)(hb + 4);
    const float2 hc = *(const float2*)(hb + 8);
    if (active) {
        float acc = lb[r];
        acc = fmaf(ha.x,  lW[r * H + 0], acc);
        acc = fmaf(ha.y,  lW[r * H + 1], acc);
        acc = fmaf(ha.z,  lW[r * H + 2], acc);
        acc = fmaf(ha.w,  lW[r * H + 3], acc);
        acc = fmaf(hbv.x, lW[r * H + 4], acc);
        acc = fmaf(hbv.y, lW[r * H + 5], acc);
        acc = fmaf(hbv.z, lW[r * H + 6], acc);
        acc = fmaf(hbv.w, lW[r * H + 7], acc);
        acc = fmaf(hc.x,  lW[r * H + 8], acc);
        acc = fmaf(hc.y,  lW[r * H + 9], acc);
        out[(size_t)bb * H + r] = acc;
    }
}

extern "C" void kernel_launch(void* const* d_in, const int* in_sizes, int n_in,
                              void* d_out, int out_size, void* d_ws, size_t ws_size,
                              hipStream_t stream) {
    const float* inputs = (const float*)d_in[0];  // [8192, 2048, 2]
    const float* A      = (const float*)d_in[1];  // [10, 10]
    const float* W_in   = (const float*)d_in[2];  // [10, 2]
    const float* b_mod  = (const float*)d_in[3];  // [10]
    const float* lin_W  = (const float*)d_in[4];  // [10, 10]
    const float* lin_b  = (const float*)d_in[5];  // [10]
    float* out = (float*)d_out;                   // [8192, 10]
    float* Bmat = (float*)d_ws;                   // 100 floats scratch

    expm_kernel<<<1, 128, 0, stream>>>(A, Bmat);
    const int nblocks = (BATCH + GPW - 1) / GPW;  // 1366
    rnn_kernel<<<nblocks, 64, 0, stream>>>(inputs, Bmat, W_in, b_mod,
                                           lin_W, lin_b, out);
}